// Round 10
// baseline (76.029 us; speedup 1.0000x reference)
//
#include <hip/hip_runtime.h>
#include <hip/hip_bf16.h>

// Problem constants (match reference setup_inputs)
constexpr int Bb = 64;
constexpr int T  = 4096;
constexpr int D  = 256;   // K
constexpr int A  = 10;
constexpr size_t ANCHORS_N  = (size_t)T * A * 2;         // 81920
constexpr size_t PER_TENSOR = (size_t)Bb * T * A * 2;    // 5242880
constexpr int M      = Bb * T;        // 262144 rows
constexpr int MT     = M / 16;        // 16384 m-tiles of 16 rows
constexpr int NBLK   = 512;           // 256-thread blocks (4 waves); 2 blocks/CU, all resident
constexpr int NWAVES = NBLK * 4;      // 2048 waves
constexpr int TPW    = MT / NWAVES;   // 8 tiles per wave

typedef __attribute__((ext_vector_type(8))) short short8v;  // 8 bf16
typedef __attribute__((ext_vector_type(4))) float f32x4;    // MFMA acc

__device__ __forceinline__ unsigned short f2b(float f) {    // RNE (pk-fusable)
    return __builtin_bit_cast(unsigned short, __float2bfloat16(f));
}

// GEMM: [M x 256] * [256 x 48] (20 cls | 20 bbox | 8 pad), MFMA 16x16x32 bf16.
// A-frag: lane holds A[row = lane&15][k = ks*32 + (lane>>4)*8 + e]  (R4-verified)
// C-frag: lane reg r -> C[row = (lane>>4)*4 + r][col = lane&15]
//
// x staged per-wave via global_load_lds in HALF-K tiles (16 rows x 128 floats
// = 8 KB, 8 load-instrs), double-buffered => 16 KB/wave, 64 KB/block,
// 2 blocks/CU = 2 waves/SIMD (2x R9's TLP). R7-verified both-sides
// chunk^(row&7) swizzle (8 lanes/bank-group = conflict-free floor).
// R9-verified discipline: dense LDS-funneled epilogue (EXACTLY 6 stores/tile)
// + aged exact-counted waits: phase0 vmcnt(14), phase1 vmcnt(8), vmcnt(0)
// only at the final half-tile. Never a drain in steady state.
__global__ __launch_bounds__(256, 2) void rpn_mfma(
    const float* __restrict__ x,
    const float* __restrict__ Wc, const float* __restrict__ bc,
    const float* __restrict__ Wb, const float* __restrict__ bb,
    float* __restrict__ out_anch, float* __restrict__ out_prop,
    float* __restrict__ out_cls,  float* __restrict__ out_bbox)
{
    __shared__ float xs[4][2][16 * 128];   // [wave][buf][16 rows x 128] = 64 KB

    const int tid  = threadIdx.x;
    const int w    = tid >> 6;
    const int lane = tid & 63;
    const int wid  = blockIdx.x * 4 + w;
    const int c    = lane & 15;   // frag col (A-row / B-col / C-col)
    const int kc   = lane >> 4;   // k-chunk 0..3
    const int sw   = c & 7;

    float* const lb0 = &xs[w][0][0];   // even (k-half 0) buffers
    float* const lb1 = &xs[w][1][0];   // odd  (k-half 1) buffers

    // per-lane source offsets for the 8 staging instructions of a half-tile
    int goff[8];
    {
        const int hi5 = lane >> 5, ch = lane & 31;
#pragma unroll
        for (int i = 0; i < 8; ++i) {
            const int r = 2 * i + hi5;
            goff[i] = r * D + ((ch ^ (r & 7)) << 2);
        }
    }

    auto stage = [&](float* lbuf, int mt, int h) {   // exactly 8 vmem load ops
        const float* gb = x + (size_t)mt * (16 * D) + h * 128;
#pragma unroll
        for (int i = 0; i < 8; ++i) {
            __builtin_amdgcn_global_load_lds(
                (const __attribute__((address_space(1))) unsigned int*)(gb + goff[i]),
                (__attribute__((address_space(3))) unsigned int*)(lbuf + i * 256),
                16, 0, 0);
        }
    };

    // ---- per-lane weight rows + biases for the 3 N-tiles ----
    const float* wrow[3];
    float bias0, bias1, bias2;
    bool  pad2;
    wrow[0] = Wc + c * D;                       bias0 = bc[c];
    wrow[1] = (c < 4) ? Wc + (16 + c) * D : Wb + (c - 4) * D;
    bias1   = (c < 4) ? bc[16 + c] : bb[c - 4];
    if (c < 8) { wrow[2] = Wb + (12 + c) * D; bias2 = bb[12 + c]; pad2 = false; }
    else       { wrow[2] = Wb;                bias2 = 0.0f;       pad2 = true;  }

    // B fragments once per wave: wf[ntile][kstep] (96 VGPR); cvt consumption
    // drains these loads before the counted-wait region begins.
    short8v wf[3][8];
#pragma unroll
    for (int nt = 0; nt < 3; ++nt) {
#pragma unroll
        for (int ks = 0; ks < 8; ++ks) {
            const float* p = wrow[nt] + kc * 8 + ks * 32;
            const float4 a = *reinterpret_cast<const float4*>(p);
            const float4 b = *reinterpret_cast<const float4*>(p + 4);
            short8v h;
            h[0] = (short)f2b(a.x); h[1] = (short)f2b(a.y);
            h[2] = (short)f2b(a.z); h[3] = (short)f2b(a.w);
            h[4] = (short)f2b(b.x); h[5] = (short)f2b(b.y);
            h[6] = (short)f2b(b.z); h[7] = (short)f2b(b.w);
            if (nt == 2 && pad2) {
#pragma unroll
                for (int e = 0; e < 8; ++e) h[e] = 0;
            }
            wf[nt][ks] = h;
        }
    }
    asm volatile("" : "+v"(bias0), "+v"(bias1), "+v"(bias2));   // resolve early

    // anchors (issued before tile-0 stages -> oldest in vmcnt order)
    {
        const int i = wid * 64 + lane;           // 131072 threads cover T*A=40960
        if (i < T * A) {
            const int t = i / A;
            const int a = i - t * A;
            const float L = fmaf((float)a, 160.0f / 9.0f, 40.0f);
            const float h = 0.5f * (L - 1.0f);
            reinterpret_cast<float2*>(out_anch)[i] = make_float2((float)t - h, (float)t + h);
        }
    }

    // prologue: both halves of tile 0 in flight
    stage(lb0, wid, 0);
    stage(lb1, wid, 1);

    auto compute_half = [&](const float* lbuf, int h, f32x4& a0, f32x4& a1, f32x4& a2) {
        const float* lrow = lbuf + c * 128;
#pragma unroll
        for (int ks = 0; ks < 4; ++ks) {
            const int ch0 = ks * 8 + kc * 2;
            const float4 qa = *reinterpret_cast<const float4*>(lrow + ((ch0 ^ sw) << 2));
            const float4 qb = *reinterpret_cast<const float4*>(lrow + (((ch0 + 1) ^ sw) << 2));
            const float v[8] = {qa.x, qa.y, qa.z, qa.w, qb.x, qb.y, qb.z, qb.w};
            short8v xh;
#pragma unroll
            for (int e = 0; e < 8; ++e) xh[e] = (short)f2b(v[e]);
            const int ksg = h * 4 + ks;
            a0 = __builtin_amdgcn_mfma_f32_16x16x32_bf16(xh, wf[0][ksg], a0, 0, 0, 0);
            a1 = __builtin_amdgcn_mfma_f32_16x16x32_bf16(xh, wf[1][ksg], a1, 0, 0, 0);
            a2 = __builtin_amdgcn_mfma_f32_16x16x32_bf16(xh, wf[2][ksg], a2, 0, 0, 0);
        }
    };

    // Dense epilogue through per-wave LDS scratch (the just-consumed odd buffer,
    // 2048 floats >= 960 needed): cls[16][20] @0, bbox @320, prop @640.
    // Then EXACTLY 6 global stores (float4 + float per tensor).
    auto epilogue = [&](float* sc, int mt,
                        const f32x4& a0, const f32x4& a1, const f32x4& a2) {
#pragma unroll
        for (int r = 0; r < 4; ++r) {
            const int row = kc * 4 + r;
            const int tf  = (mt * 16 + row) & (T - 1);

            sc[row * 20 + c] = a0[r] + bias0;                    // cls j = 0..15

            const float v1  = a1[r] + bias1;
            const float v1p = __shfl_xor(v1, 1);
            const float v2  = a2[r] + bias2;
            const float v2p = __shfl_xor(v2, 1);

            if (c < 4) {
                sc[row * 20 + 16 + c] = v1;                      // cls j = 16..19
            } else {
                const int jb = c - 4;                            // bbox 0..11
                sc[320 + row * 20 + jb] = v1;
                if (!(jb & 1)) {
                    const int   an = jb >> 1;
                    const float L  = fmaf((float)an, 160.0f / 9.0f, 40.0f);
                    const float ctr = fmaf(v1, L, (float)tf);
                    const float pl  = __expf(v1p) * L;
                    const float hh  = 0.5f * (pl - 1.0f);
                    const float s = fminf(fmaxf(ctr - hh, 0.0f), (float)(T - 1));
                    const float e = fminf(fmaxf(ctr + hh, 0.0f), (float)(T - 1));
                    *reinterpret_cast<float2*>(&sc[640 + row * 20 + jb]) = make_float2(s, e);
                }
            }
            if (c < 8) {
                const int jb = 12 + c;                           // bbox 12..19
                sc[320 + row * 20 + jb] = v2;
                if (!(jb & 1)) {
                    const int   an = jb >> 1;
                    const float L  = fmaf((float)an, 160.0f / 9.0f, 40.0f);
                    const float ctr = fmaf(v2, L, (float)tf);
                    const float pl  = __expf(v2p) * L;
                    const float hh  = 0.5f * (pl - 1.0f);
                    const float s = fminf(fmaxf(ctr - hh, 0.0f), (float)(T - 1));
                    const float e = fminf(fmaxf(ctr + hh, 0.0f), (float)(T - 1));
                    *reinterpret_cast<float2*>(&sc[640 + row * 20 + jb]) = make_float2(s, e);
                }
            }
        }
        // dense readback: per tensor 1280 B = 64-lane float4 (1024 B) + float (256 B)
        const size_t base = (size_t)mt * 320;
        const float4 q0 = *reinterpret_cast<const float4*>(sc + lane * 4);
        const float  s0 = sc[256 + lane];
        const float4 q1 = *reinterpret_cast<const float4*>(sc + 320 + lane * 4);
        const float  s1 = sc[320 + 256 + lane];
        const float4 q2 = *reinterpret_cast<const float4*>(sc + 640 + lane * 4);
        const float  s2 = sc[640 + 256 + lane];
        *reinterpret_cast<float4*>(out_cls  + base + lane * 4) = q0;   // store 1
        out_cls [base + 256 + lane] = s0;                              // store 2
        *reinterpret_cast<float4*>(out_bbox + base + lane * 4) = q1;   // store 3
        out_bbox[base + 256 + lane] = s1;                              // store 4
        *reinterpret_cast<float4*>(out_prop + base + lane * 4) = q2;   // store 5
        out_prop[base + 256 + lane] = s2;                              // store 6
    };

    // steady state per tile t:
    //  phase0: wait vmcnt(14)  [queue: loads(h0,t):8 | stores(t-1):6 | loads(h1,t):8]
    //          compute h0; stage h0(t+1)
    //  phase1: wait vmcnt(8)   [queue: loads(h1,t):8 | loads(h0,t+1):8]
    //          compute h1; epilogue (6 stores); stage h1(t+1)
#pragma unroll 1
    for (int t = 0; t < TPW; ++t) {
        const int mt = wid + t * NWAVES;
        f32x4 a0 = {0,0,0,0}, a1 = {0,0,0,0}, a2 = {0,0,0,0};

        // ---- phase 0 ----
        if (t == 0) { asm volatile("s_waitcnt vmcnt(8)"  ::: "memory"); }
        else        { asm volatile("s_waitcnt vmcnt(14)" ::: "memory"); }
        __builtin_amdgcn_sched_barrier(0);
        compute_half(lb0, 0, a0, a1, a2);
        if (t + 1 < TPW) stage(lb0, wid + (t + 1) * NWAVES, 0);

        // ---- phase 1 ----
        if (t + 1 < TPW) { asm volatile("s_waitcnt vmcnt(8)" ::: "memory"); }
        else             { asm volatile("s_waitcnt vmcnt(0)" ::: "memory"); }
        __builtin_amdgcn_sched_barrier(0);
        compute_half(lb1, 1, a0, a1, a2);
        epilogue(lb1, mt, a0, a1, a2);   // scratch = odd buffer just consumed
        if (t + 1 < TPW) stage(lb1, wid + (t + 1) * NWAVES, 1);
    }
}

extern "C" void kernel_launch(void* const* d_in, const int* in_sizes, int n_in,
                              void* d_out, int out_size, void* d_ws, size_t ws_size,
                              hipStream_t stream) {
    const float* x  = (const float*)d_in[0];
    const float* Wc = (const float*)d_in[1];
    const float* bc = (const float*)d_in[2];
    const float* Wb = (const float*)d_in[3];
    const float* bb = (const float*)d_in[4];

    float* out     = (float*)d_out;
    float* anchors = out;
    float* prop    = out + ANCHORS_N;
    float* cls     = out + ANCHORS_N + PER_TENSOR;
    float* bbox    = out + ANCHORS_N + 2 * PER_TENSOR;

    rpn_mfma<<<NBLK, 256, 0, stream>>>(x, Wc, bc, Wb, bb, anchors, prop, cls, bbox);
}

// Round 12
// 61.292 us; speedup vs baseline: 1.2404x; 1.2404x over previous
//
#include <hip/hip_runtime.h>
#include <hip/hip_bf16.h>

// Problem constants (match reference setup_inputs)
constexpr int Bb = 64;
constexpr int T  = 4096;
constexpr int D  = 256;   // K
constexpr int A  = 10;
constexpr size_t ANCHORS_N  = (size_t)T * A * 2;         // 81920
constexpr size_t PER_TENSOR = (size_t)Bb * T * A * 2;    // 5242880
constexpr int M      = Bb * T;        // 262144 rows
constexpr int MT     = M / 16;        // 16384 m-tiles of 16 rows
constexpr int NBLK   = 512;           // 128-thread blocks (2 waves); 2 blocks/CU
constexpr int NWAVES = NBLK * 2;      // 1024 waves
constexpr int TPW    = MT / NWAVES;   // 16 tiles per wave

typedef __attribute__((ext_vector_type(8))) short short8v;  // 8 bf16
typedef __attribute__((ext_vector_type(4))) float f32x4;    // MFMA acc
typedef __attribute__((ext_vector_type(4))) float vf4;      // clang vec for NT stores
typedef __attribute__((ext_vector_type(2))) float vf2;

__device__ __forceinline__ unsigned short f2b(float f) {    // RNE (pk-fusable)
    return __builtin_bit_cast(unsigned short, __float2bfloat16(f));
}

// GEMM: [M x 256] * [256 x 48] (20 cls | 20 bbox | 8 pad), MFMA 16x16x32 bf16.
// A-frag: lane holds A[row = lane&15][k = ks*32 + (lane>>4)*8 + e]  (R4-verified)
// C-frag: lane reg r -> C[row = (lane>>4)*4 + r][col = lane&15]
//
// R9 structure verbatim (best so far, 71.6 us): global_load_lds 16 KB tiles,
// dbuf, both-sides chunk^(row&7) swizzle, aged exact-counted waits
// (vmcnt(22) retires exactly the one-iteration-old tile; stores(t-1)=6 and
// loads(t+1)=16 stay in flight). SINGLE CHANGE vs R9: all output stores are
// NON-TEMPORAL — outputs are never re-read, so keeping them out of L2/L3
// preserves x residency (FETCH was ~133 MB: x half-resident across replays;
// the 63 MB/replay of output allocation was evicting it).
__global__ __launch_bounds__(128, 1) void rpn_mfma(
    const float* __restrict__ x,
    const float* __restrict__ Wc, const float* __restrict__ bc,
    const float* __restrict__ Wb, const float* __restrict__ bb,
    float* __restrict__ out_anch, float* __restrict__ out_prop,
    float* __restrict__ out_cls,  float* __restrict__ out_bbox)
{
    __shared__ float xs[2][2][16 * 256];   // [wave][buf][16 rows x 256] = 64 KB

    const int tid  = threadIdx.x;
    const int w    = tid >> 6;
    const int lane = tid & 63;
    const int wid  = blockIdx.x * 2 + w;
    const int c    = lane & 15;   // frag col (A-row / B-col / C-col)
    const int kc   = lane >> 4;   // k-chunk 0..3
    const int sw   = c & 7;

    float* const lbA = &xs[w][0][0];
    float* const lbB = &xs[w][1][0];

    auto stage = [&](float* lbuf, int mt) {   // exactly 16 vmem load ops
        const float* gbase = x + (size_t)mt * (16 * D);
#pragma unroll
        for (int r = 0; r < 16; ++r) {
            // lane l carries global chunk (l ^ (r&7)) -> linear LDS chunk l
            const float* g = gbase + r * D + ((lane ^ (r & 7)) << 2);
            __builtin_amdgcn_global_load_lds(
                (const __attribute__((address_space(1))) unsigned int*)g,
                (__attribute__((address_space(3))) unsigned int*)(lbuf + r * 256),
                16, 0, 0);
        }
    };

    // ---- per-lane weight rows + biases for the 3 N-tiles ----
    const float* wrow[3];
    float bias0, bias1, bias2;
    bool  pad2;
    wrow[0] = Wc + c * D;                       bias0 = bc[c];
    wrow[1] = (c < 4) ? Wc + (16 + c) * D : Wb + (c - 4) * D;
    bias1   = (c < 4) ? bc[16 + c] : bb[c - 4];
    if (c < 8) { wrow[2] = Wb + (12 + c) * D; bias2 = bb[12 + c]; pad2 = false; }
    else       { wrow[2] = Wb;                bias2 = 0.0f;       pad2 = true;  }

    // B fragments once per wave: wf[ntile][kstep] (96 VGPR); cvt consumption
    // drains these loads before the counted-wait region begins.
    short8v wf[3][8];
#pragma unroll
    for (int nt = 0; nt < 3; ++nt) {
#pragma unroll
        for (int ks = 0; ks < 8; ++ks) {
            const float* p = wrow[nt] + kc * 8 + ks * 32;
            const float4 a = *reinterpret_cast<const float4*>(p);
            const float4 b = *reinterpret_cast<const float4*>(p + 4);
            short8v h;
            h[0] = (short)f2b(a.x); h[1] = (short)f2b(a.y);
            h[2] = (short)f2b(a.z); h[3] = (short)f2b(a.w);
            h[4] = (short)f2b(b.x); h[5] = (short)f2b(b.y);
            h[6] = (short)f2b(b.z); h[7] = (short)f2b(b.w);
            if (nt == 2 && pad2) {
#pragma unroll
                for (int e = 0; e < 8; ++e) h[e] = 0;
            }
            wf[nt][ks] = h;
        }
    }
    asm volatile("" : "+v"(bias0), "+v"(bias1), "+v"(bias2));   // resolve early

    // anchors (issued before tile-0 stage -> always oldest in vmcnt order)
    {
        const int i = wid * 64 + lane;           // 65536 threads cover T*A=40960
        if (i < T * A) {
            const int t = i / A;
            const int a = i - t * A;
            const float L = fmaf((float)a, 160.0f / 9.0f, 40.0f);
            const float h = 0.5f * (L - 1.0f);
            vf2 v; v.x = (float)t - h; v.y = (float)t + h;
            __builtin_nontemporal_store(v, reinterpret_cast<vf2*>(out_anch) + i);
        }
    }

    stage(lbA, wid);                 // tile 0 in flight

    auto compute = [&](const float* lbuf, f32x4& a0, f32x4& a1, f32x4& a2) {
        const float* lrow = lbuf + c * 256;
#pragma unroll
        for (int ks = 0; ks < 8; ++ks) {
            const int ch0 = 2 * kc;
            const float4 qa = *reinterpret_cast<const float4*>(lrow + ks * 32 + ((ch0 ^ sw) << 2));
            const float4 qb = *reinterpret_cast<const float4*>(lrow + ks * 32 + (((ch0 + 1) ^ sw) << 2));
            const float v[8] = {qa.x, qa.y, qa.z, qa.w, qb.x, qb.y, qb.z, qb.w};
            short8v xh;
#pragma unroll
            for (int e = 0; e < 8; ++e) xh[e] = (short)f2b(v[e]);
            a0 = __builtin_amdgcn_mfma_f32_16x16x32_bf16(xh, wf[0][ks], a0, 0, 0, 0);
            a1 = __builtin_amdgcn_mfma_f32_16x16x32_bf16(xh, wf[1][ks], a1, 0, 0, 0);
            a2 = __builtin_amdgcn_mfma_f32_16x16x32_bf16(xh, wf[2][ks], a2, 0, 0, 0);
        }
    };

    // Dense epilogue through per-wave LDS scratch (the buffer just consumed):
    // layout (floats): cls[16][20] @0, bbox[16][20] @320, prop[16][20] @640.
    // Then EXACTLY 6 global stores (float4 + float per tensor), nontemporal.
    auto epilogue = [&](float* sc, int mt,
                        const f32x4& a0, const f32x4& a1, const f32x4& a2) {
#pragma unroll
        for (int r = 0; r < 4; ++r) {
            const int row = kc * 4 + r;
            const int tf  = (mt * 16 + row) & (T - 1);

            sc[row * 20 + c] = a0[r] + bias0;                    // cls j = 0..15

            const float v1  = a1[r] + bias1;
            const float v1p = __shfl_xor(v1, 1);
            const float v2  = a2[r] + bias2;
            const float v2p = __shfl_xor(v2, 1);

            if (c < 4) {
                sc[row * 20 + 16 + c] = v1;                      // cls j = 16..19
            } else {
                const int jb = c - 4;                            // bbox 0..11
                sc[320 + row * 20 + jb] = v1;
                if (!(jb & 1)) {
                    const int   an = jb >> 1;
                    const float L  = fmaf((float)an, 160.0f / 9.0f, 40.0f);
                    const float ctr = fmaf(v1, L, (float)tf);
                    const float pl  = __expf(v1p) * L;
                    const float hh  = 0.5f * (pl - 1.0f);
                    const float s = fminf(fmaxf(ctr - hh, 0.0f), (float)(T - 1));
                    const float e = fminf(fmaxf(ctr + hh, 0.0f), (float)(T - 1));
                    *reinterpret_cast<float2*>(&sc[640 + row * 20 + jb]) = make_float2(s, e);
                }
            }
            if (c < 8) {
                const int jb = 12 + c;                           // bbox 12..19
                sc[320 + row * 20 + jb] = v2;
                if (!(jb & 1)) {
                    const int   an = jb >> 1;
                    const float L  = fmaf((float)an, 160.0f / 9.0f, 40.0f);
                    const float ctr = fmaf(v2, L, (float)tf);
                    const float pl  = __expf(v2p) * L;
                    const float hh  = 0.5f * (pl - 1.0f);
                    const float s = fminf(fmaxf(ctr - hh, 0.0f), (float)(T - 1));
                    const float e = fminf(fmaxf(ctr + hh, 0.0f), (float)(T - 1));
                    *reinterpret_cast<float2*>(&sc[640 + row * 20 + jb]) = make_float2(s, e);
                }
            }
        }
        // dense readback: per tensor 1280 B = 64-lane float4 (1024 B) + float (256 B)
        const size_t base = (size_t)mt * 320;
        const vf4  q0 = *reinterpret_cast<const vf4*>(sc + lane * 4);
        const float s0 = sc[256 + lane];
        const vf4  q1 = *reinterpret_cast<const vf4*>(sc + 320 + lane * 4);
        const float s1 = sc[320 + 256 + lane];
        const vf4  q2 = *reinterpret_cast<const vf4*>(sc + 640 + lane * 4);
        const float s2 = sc[640 + 256 + lane];
        __builtin_nontemporal_store(q0, reinterpret_cast<vf4*>(out_cls  + base + lane * 4)); // 1
        __builtin_nontemporal_store(s0, out_cls  + base + 256 + lane);                       // 2
        __builtin_nontemporal_store(q1, reinterpret_cast<vf4*>(out_bbox + base + lane * 4)); // 3
        __builtin_nontemporal_store(s1, out_bbox + base + 256 + lane);                       // 4
        __builtin_nontemporal_store(q2, reinterpret_cast<vf4*>(out_prop + base + lane * 4)); // 5
        __builtin_nontemporal_store(s2, out_prop + base + 256 + lane);                       // 6
    };

    float* cur = lbA;
    float* nxt = lbB;

#pragma unroll 1
    for (int t = 0; t < TPW; ++t) {
        const int mt = wid + t * NWAVES;

        if (t + 1 < TPW) stage(nxt, wid + (t + 1) * NWAVES);   // 16 newest loads

        // queue: [loads(t):16][stores(t-1):6][loads(t+1):16]
        if (t == 0)           { asm volatile("s_waitcnt vmcnt(16)" ::: "memory"); }
        else if (t + 1 < TPW) { asm volatile("s_waitcnt vmcnt(22)" ::: "memory"); }
        else                  { asm volatile("s_waitcnt vmcnt(0)"  ::: "memory"); }
        __builtin_amdgcn_sched_barrier(0);

        f32x4 a0 = {0,0,0,0}, a1 = {0,0,0,0}, a2 = {0,0,0,0};
        compute(cur, a0, a1, a2);
        epilogue(cur, mt, a0, a1, a2);   // scratch = buffer just consumed

        float* tmp = cur; cur = nxt; nxt = tmp;
    }
}

extern "C" void kernel_launch(void* const* d_in, const int* in_sizes, int n_in,
                              void* d_out, int out_size, void* d_ws, size_t ws_size,
                              hipStream_t stream) {
    const float* x  = (const float*)d_in[0];
    const float* Wc = (const float*)d_in[1];
    const float* bc = (const float*)d_in[2];
    const float* Wb = (const float*)d_in[3];
    const float* bb = (const float*)d_in[4];

    float* out     = (float*)d_out;
    float* anchors = out;
    float* prop    = out + ANCHORS_N;
    float* cls     = out + ANCHORS_N + PER_TENSOR;
    float* bbox    = out + ANCHORS_N + 2 * PER_TENSOR;

    rpn_mfma<<<NBLK, 128, 0, stream>>>(x, Wc, bc, Wb, bb, anchors, prop, cls, bbox);
}